// Round 1
// baseline (39.441 us; speedup 1.0000x reference)
//
#include <hip/hip_runtime.h>

#define TT 256
#define BB 256
#define DD 128
// out: outs[TT][BB][128] then hx[BB][128] then cx[BB][128]

__device__ __forceinline__ float rdlane(float v, int l) {
    return __int_as_float(__builtin_amdgcn_readlane(__float_as_int(v), l));
}
__device__ __forceinline__ float frcp(float x) { return __builtin_amdgcn_rcpf(x); }
__device__ __forceinline__ float fastcos(float z) {
    float r = z * 0.15915494309189535f;      // revolutions
    r = __builtin_amdgcn_fractf(r);          // exact periodic reduction
    return __builtin_amdgcn_cosf(r);
}

// Kernel 1: angles A[b*TT + t] = {a_f, a_i, a_u, a_o},
// a_g = x[t,b,:] . Wg[0,0:128] + bg[0] + pg[0]
__global__ __launch_bounds__(256) void k_angles(
    const float* __restrict__ x,
    const float* __restrict__ Wf, const float* __restrict__ bf, const float* __restrict__ pf,
    const float* __restrict__ Wi, const float* __restrict__ bi, const float* __restrict__ pi,
    const float* __restrict__ Wu, const float* __restrict__ bu, const float* __restrict__ pu,
    const float* __restrict__ Wo, const float* __restrict__ bo, const float* __restrict__ po,
    float4* __restrict__ A)
{
    __shared__ float4 w4[4][32];             // row 0, cols 0..127 of each W
    float* w = reinterpret_cast<float*>(w4);
    int tid = threadIdx.x;
    for (int k = tid; k < 512; k += 256) {
        int g = k >> 7, j = k & 127;
        const float* W = (g == 0) ? Wf : (g == 1) ? Wi : (g == 2) ? Wu : Wo;
        w[g * 128 + j] = W[j];
    }
    __syncthreads();

    int r = blockIdx.x * 256 + tid;          // r = t*BB + b  (lanes -> consecutive b)
    int t = r >> 8, b = r & 255;
    const float4* xr = reinterpret_cast<const float4*>(x + (size_t)r * DD);

    float af = bf[0] + pf[0];
    float ai = bi[0] + pi[0];
    float au = bu[0] + pu[0];
    float ao = bo[0] + po[0];
    #pragma unroll
    for (int k = 0; k < 32; ++k) {
        float4 v  = xr[k];
        float4 f4 = w4[0][k], i4 = w4[1][k], u4 = w4[2][k], o4 = w4[3][k];
        af = fmaf(v.x, f4.x, fmaf(v.y, f4.y, fmaf(v.z, f4.z, fmaf(v.w, f4.w, af))));
        ai = fmaf(v.x, i4.x, fmaf(v.y, i4.y, fmaf(v.z, i4.z, fmaf(v.w, i4.w, ai))));
        au = fmaf(v.x, u4.x, fmaf(v.y, u4.y, fmaf(v.z, u4.z, fmaf(v.w, u4.w, au))));
        ao = fmaf(v.x, o4.x, fmaf(v.y, o4.y, fmaf(v.z, o4.z, fmaf(v.w, o4.w, ao))));
    }
    A[b * TT + t] = make_float4(af, ai, au, ao);
}

// Kernel 2: per-sample serial recurrence + broadcast writes.
// One block (1 wave, 64 lanes) per sample b. Lanes 0..3 own gates f,i,u,o
// (all lanes redundantly compute lane&3's gate; readlane broadcasts).
__global__ __launch_bounds__(64) void k_recur(
    const float4* __restrict__ A,
    const float* __restrict__ Wf, const float* __restrict__ Wi,
    const float* __restrict__ Wu, const float* __restrict__ Wo,
    float* __restrict__ out)
{
    int b = blockIdx.x;
    int lane = threadIdx.x;
    __shared__ float As[4][260];             // pad 260: conflict-free column reads

    // stage this sample's angle column (coalesced float4 loads), transposed
    #pragma unroll
    for (int k = 0; k < 4; ++k) {
        int t = lane + 64 * k;
        float4 a4 = A[b * TT + t];
        As[0][t] = a4.x; As[1][t] = a4.y; As[2][t] = a4.z; As[3][t] = a4.w;
    }

    // S_g = sum Wg[0, 128:256] (h-feedback weight; h is constant over hidden dim)
    int g = lane & 3;
    const float* W = (g == 0) ? Wf : (g == 1) ? Wi : (g == 2) ? Wu : Wo;
    const float4* W4 = reinterpret_cast<const float4*>(W + 128);
    float S = 0.f;
    #pragma unroll
    for (int k = 0; k < 32; ++k) {
        float4 v = W4[k];
        S += (v.x + v.y) + (v.z + v.w);
    }
    // unified activation: act = Aact * sigmoid(kk*v) + Bact  (tanh(v)=2*sig(2v)-1)
    float kk   = (g == 2) ? -2.f : -1.f;     // negated for exp(-k v)
    float Aact = (g == 2) ?  2.f :  1.f;
    float Bact = (g == 2) ? -1.f :  0.f;

    __syncthreads();

    float c = 0.f, h = 0.f;
    float a_cur = As[g][0];
    float* outp = out + b * 128 + lane * 2;

    for (int t = 0; t < TT; ++t) {
        float a_next = As[g][t + 1];         // prefetch (t=255 reads pad, unused)
        float z = fmaf(h, S, a_cur);
        float v = fastcos(z);
        float e = __expf(kk * v);
        float s = frcp(1.f + e);
        float act = fmaf(Aact, s, Bact);
        float fv = rdlane(act, 0);
        float iv = rdlane(act, 1);
        float uv = rdlane(act, 2);
        float ov = rdlane(act, 3);
        c = fmaf(fv, c, iv * uv);
        float e2 = __expf(2.f * c);
        float th = 1.f - 2.f * frcp(1.f + e2);
        h = ov * th;
        *reinterpret_cast<float2*>(outp + (size_t)t * (BB * 128)) = make_float2(h, h);
        a_cur = a_next;
    }
    float* hx = out + (size_t)TT * BB * 128;
    float* cx = hx + BB * 128;
    *reinterpret_cast<float2*>(hx + b * 128 + lane * 2) = make_float2(h, h);
    *reinterpret_cast<float2*>(cx + b * 128 + lane * 2) = make_float2(c, c);
}

extern "C" void kernel_launch(void* const* d_in, const int* in_sizes, int n_in,
                              void* d_out, int out_size, void* d_ws, size_t ws_size,
                              hipStream_t stream) {
    const float* x = (const float*)d_in[0];
    const float *Wf, *bf, *pf, *Wi, *bi, *pi, *Wu, *bu, *pu, *Wo, *bo, *po;
    if (n_in >= 13 && in_sizes[3] == 8 && in_sizes[4] == 2048) {
        // setup_inputs dict order: (Wf,bf,pf),(Wi,bi,pi),(Wu,bu,pu),(Wo,bo,po)
        Wf = (const float*)d_in[1];  bf = (const float*)d_in[2];  pf = (const float*)d_in[3];
        Wi = (const float*)d_in[4];  bi = (const float*)d_in[5];  pi = (const float*)d_in[6];
        Wu = (const float*)d_in[7];  bu = (const float*)d_in[8];  pu = (const float*)d_in[9];
        Wo = (const float*)d_in[10]; bo = (const float*)d_in[11]; po = (const float*)d_in[12];
    } else {
        // reference signature order: Wf,bf,Wi,bi,Wu,bu,Wo,bo,pf,pi,pu,po
        Wf = (const float*)d_in[1];  bf = (const float*)d_in[2];
        Wi = (const float*)d_in[3];  bi = (const float*)d_in[4];
        Wu = (const float*)d_in[5];  bu = (const float*)d_in[6];
        Wo = (const float*)d_in[7];  bo = (const float*)d_in[8];
        pf = (const float*)d_in[9];  pi = (const float*)d_in[10];
        pu = (const float*)d_in[11]; po = (const float*)d_in[12];
    }
    float4* A = (float4*)d_ws;                 // 65536 * 16B = 1 MiB scratch

    k_angles<<<dim3(256), dim3(256), 0, stream>>>(
        x, Wf, bf, pf, Wi, bi, pi, Wu, bu, pu, Wo, bo, po, A);
    k_recur<<<dim3(256), dim3(64), 0, stream>>>(
        A, Wf, Wi, Wu, Wo, (float*)d_out);
}